// Round 1
// baseline (336.884 us; speedup 1.0000x reference)
//
#include <hip/hip_runtime.h>
#include <cstdint>
#include <cstddef>

#define H      640
#define RH     256
#define NE     5
#define NA     40          // NE * rank
#define NTOK   32768
#define SCAL   2.0f        // alpha/rank = 16/8
#define BK     32

__device__ __forceinline__ float4 ld4(const float* p) {
    return *reinterpret_cast<const float4*>(p);
}

// ---------------------------------------------------------------------------
// Kernel 1: router (x@W1 -> silu -> @W2 -> softmax -> top2) + low = x@A (all
// experts). BM=64 tokens/block, BN=256 (full router hidden), BK=32.
// 128 threads: tm=tid>>4 (8 row-groups of 8 tokens), tn=tid&15 (16 col-groups,
// each thread owns cols {tn*4+i + 64q}). Low: mlow=tid>>1 token, g=tid&1 owns
// 20 of the 40 (expert,rank) columns.
// Writes per token: route_c[16] = w_k*SCAL*low_k, route_idx[2].
// ---------------------------------------------------------------------------
__global__ __launch_bounds__(128, 2)
void k_router(const float* __restrict__ x, const float* __restrict__ W1,
              const float* __restrict__ b1v, const float* __restrict__ W2,
              const float* __restrict__ b2v, const float* __restrict__ A,
              float* __restrict__ route_c, int* __restrict__ route_idx)
{
    __shared__ float xs[BK][64];
    __shared__ float ws[BK][RH];
    __shared__ float as_[BK][NA];
    __shared__ float w2s[RH * NE];
    __shared__ float b1s[RH];
    __shared__ float low_lds[64][NA];

    const int tid  = threadIdx.x;
    const int row0 = blockIdx.x * 64;
    const int tm   = tid >> 4;
    const int tn   = tid & 15;
    const int mlow = tid >> 1;
    const int g    = tid & 1;

    for (int i = tid; i < RH * NE; i += 128) w2s[i] = W2[i];
    for (int i = tid; i < RH; i += 128) b1s[i] = b1v[i];

    float acc[8][16];
    #pragma unroll
    for (int i = 0; i < 8; i++)
        #pragma unroll
        for (int j = 0; j < 16; j++) acc[i][j] = 0.f;
    float accl[20];
    #pragma unroll
    for (int j = 0; j < 20; j++) accl[j] = 0.f;

    for (int k0 = 0; k0 < H; k0 += BK) {
        __syncthreads();
        // stage x tile [64 tokens][BK] transposed -> xs[k][m]
        #pragma unroll
        for (int i = 0; i < 4; i++) {
            int idx4 = tid + i * 128;          // 0..511 float4s
            int m  = idx4 >> 3;                // 0..63
            int kk = (idx4 & 7) * 4;
            float4 v = ld4(x + (size_t)(row0 + m) * H + k0 + kk);
            xs[kk + 0][m] = v.x; xs[kk + 1][m] = v.y;
            xs[kk + 2][m] = v.z; xs[kk + 3][m] = v.w;
        }
        // stage W1 tile [BK][256]
        #pragma unroll
        for (int i = 0; i < 16; i++) {
            int idx4 = tid + i * 128;          // 0..2047
            int row = idx4 >> 6;               // 0..31
            int cg  = idx4 & 63;
            *reinterpret_cast<float4*>(&ws[row][cg * 4]) =
                ld4(W1 + (size_t)(k0 + row) * RH + cg * 4);
        }
        // stage A tile [BK][40]; A is [E][H][R], as_[k][e*8+r] = A[e][k0+k][r]
        #pragma unroll
        for (int i = 0; i < 3; i++) {
            int idx4 = tid + i * 128;          // need 0..319
            if (idx4 < 320) {
                int row = idx4 / 10;
                int cc  = (idx4 % 10) * 4;
                int e = cc >> 3, r = cc & 7;
                *reinterpret_cast<float4*>(&as_[row][cc]) =
                    ld4(A + ((size_t)e * H + (k0 + row)) * 8 + r);
            }
        }
        __syncthreads();

        for (int kk = 0; kk < BK; kk++) {
            float a8[8];
            *reinterpret_cast<float4*>(&a8[0]) = *reinterpret_cast<const float4*>(&xs[kk][tm * 8]);
            *reinterpret_cast<float4*>(&a8[4]) = *reinterpret_cast<const float4*>(&xs[kk][tm * 8 + 4]);
            float bb[16];
            #pragma unroll
            for (int q = 0; q < 4; q++)
                *reinterpret_cast<float4*>(&bb[q * 4]) =
                    *reinterpret_cast<const float4*>(&ws[kk][(tn + 16 * q) * 4]);
            #pragma unroll
            for (int i = 0; i < 8; i++)
                #pragma unroll
                for (int j = 0; j < 16; j++)
                    acc[i][j] = fmaf(a8[i], bb[j], acc[i][j]);

            float xv = xs[kk][mlow];
            float bl[20];
            #pragma unroll
            for (int q = 0; q < 5; q++)
                *reinterpret_cast<float4*>(&bl[q * 4]) =
                    *reinterpret_cast<const float4*>(&as_[kk][g * 20 + q * 4]);
            #pragma unroll
            for (int j = 0; j < 20; j++) accl[j] = fmaf(xv, bl[j], accl[j]);
        }
    }

    // ---- epilogue: silu + b1, partial logits over this thread's 16 cols ----
    float part[8][5];
    #pragma unroll
    for (int m = 0; m < 8; m++)
        #pragma unroll
        for (int e = 0; e < 5; e++) part[m][e] = 0.f;

    #pragma unroll
    for (int q = 0; q < 4; q++)
        #pragma unroll
        for (int i4 = 0; i4 < 4; i4++) {
            int col = (tn + 16 * q) * 4 + i4;
            float bbias = b1s[col];
            float w2r[5];
            #pragma unroll
            for (int e = 0; e < 5; e++) w2r[e] = w2s[col * 5 + e];
            #pragma unroll
            for (int m = 0; m < 8; m++) {
                float v = acc[m][q * 4 + i4] + bbias;
                float s = __fdividef(v, 1.f + __expf(-v));   // silu
                #pragma unroll
                for (int e = 0; e < 5; e++) part[m][e] = fmaf(s, w2r[e], part[m][e]);
            }
        }

    // reduce partial logits across the 16 tn-lanes (within-wave butterflies)
    #pragma unroll
    for (int m = 0; m < 8; m++)
        #pragma unroll
        for (int e = 0; e < 5; e++) {
            float v = part[m][e];
            v += __shfl_xor(v, 1);
            v += __shfl_xor(v, 2);
            v += __shfl_xor(v, 4);
            v += __shfl_xor(v, 8);
            part[m][e] = v;
        }

    // publish low values
    #pragma unroll
    for (int j = 0; j < 20; j++) low_lds[mlow][g * 20 + j] = accl[j];
    __syncthreads();

    if (tn == 0) {
        float bb0 = b2v[0], bb1 = b2v[1], bb2 = b2v[2], bb3 = b2v[3], bb4 = b2v[4];
        #pragma unroll
        for (int m = 0; m < 8; m++) {
            int tl = tm * 8 + m;
            float l0 = part[m][0] + bb0;
            float l1 = part[m][1] + bb1;
            float l2 = part[m][2] + bb2;
            float l3 = part[m][3] + bb3;
            float l4 = part[m][4] + bb4;
            int   i0 = 0;  float m0 = l0;
            int   i1 = -1; float m1 = -3.4e38f;
            if (l1 > m0) { m1 = m0; i1 = i0; m0 = l1; i0 = 1; } else if (l1 > m1) { m1 = l1; i1 = 1; }
            if (l2 > m0) { m1 = m0; i1 = i0; m0 = l2; i0 = 2; } else if (l2 > m1) { m1 = l2; i1 = 2; }
            if (l3 > m0) { m1 = m0; i1 = i0; m0 = l3; i0 = 3; } else if (l3 > m1) { m1 = l3; i1 = 3; }
            if (l4 > m0) { m1 = m0; i1 = i0; m0 = l4; i0 = 4; } else if (l4 > m1) { m1 = l4; i1 = 4; }
            // softmax over top-2 == normalized top-2 softmax weights
            float w1r = __expf(m1 - m0);
            float inv = __fdividef(1.f, 1.f + w1r);
            float c0 = inv * SCAL;
            float c1 = w1r * inv * SCAL;
            int gt = row0 + tl;
            #pragma unroll
            for (int r = 0; r < 8; r++)
                route_c[(size_t)gt * 16 + r] = c0 * low_lds[tl][i0 * 8 + r];
            #pragma unroll
            for (int r = 0; r < 8; r++)
                route_c[(size_t)gt * 16 + 8 + r] = c1 * low_lds[tl][i1 * 8 + r];
            route_idx[gt * 2 + 0] = i0;
            route_idx[gt * 2 + 1] = i1;
        }
    }
}

// ---------------------------------------------------------------------------
// Kernel 2: out[t] = base[t] + sum_j c[t][j] * Bm_row[idx_j][:]
// All of Bm (40x640 f32 = 102.4 KB) staged in LDS. 512 thr (8 waves), one
// wave per token at a time; grid = 256 blocks * 128 tokens.
// ---------------------------------------------------------------------------
__global__ __launch_bounds__(512)
void k_combine(const float* __restrict__ base, const float* __restrict__ Bm,
               const float* __restrict__ route_c, const int* __restrict__ route_idx,
               float* __restrict__ out)
{
    __shared__ float bs[NA][H];
    const int tid = threadIdx.x;
    for (int i4 = tid; i4 < NA * H / 4; i4 += 512)
        reinterpret_cast<float4*>(&bs[0][0])[i4] = reinterpret_cast<const float4*>(Bm)[i4];
    __syncthreads();

    const int w    = tid >> 6;
    const int lane = tid & 63;

    for (int it = 0; it < 16; it++) {
        int t = blockIdx.x * 128 + w * 16 + it;
        t = __builtin_amdgcn_readfirstlane(t);
        const int e0 = route_idx[t * 2 + 0];
        const int e1 = route_idx[t * 2 + 1];
        float cc[16];
        #pragma unroll
        for (int q = 0; q < 4; q++)
            *reinterpret_cast<float4*>(&cc[q * 4]) = ld4(route_c + (size_t)t * 16 + q * 4);

        const float* brow0 = &bs[e0 * 8][0];
        const float* brow1 = &bs[e1 * 8][0];
        const float* bp = base + (size_t)t * H;
        float*       op = out  + (size_t)t * H;

        #pragma unroll
        for (int i = 0; i < 2; i++) {
            int h = i * 256 + lane * 4;
            float4 a = ld4(bp + h);
            #pragma unroll
            for (int j = 0; j < 8; j++) {
                float4 bv = *reinterpret_cast<const float4*>(brow0 + j * H + h);
                a.x = fmaf(cc[j], bv.x, a.x); a.y = fmaf(cc[j], bv.y, a.y);
                a.z = fmaf(cc[j], bv.z, a.z); a.w = fmaf(cc[j], bv.w, a.w);
            }
            #pragma unroll
            for (int j = 0; j < 8; j++) {
                float4 bv = *reinterpret_cast<const float4*>(brow1 + j * H + h);
                a.x = fmaf(cc[8 + j], bv.x, a.x); a.y = fmaf(cc[8 + j], bv.y, a.y);
                a.z = fmaf(cc[8 + j], bv.z, a.z); a.w = fmaf(cc[8 + j], bv.w, a.w);
            }
            *reinterpret_cast<float4*>(op + h) = a;
        }
        {
            int h = 512 + lane * 2;
            float2 a = *reinterpret_cast<const float2*>(bp + h);
            #pragma unroll
            for (int j = 0; j < 8; j++) {
                float2 bv = *reinterpret_cast<const float2*>(brow0 + j * H + h);
                a.x = fmaf(cc[j], bv.x, a.x); a.y = fmaf(cc[j], bv.y, a.y);
            }
            #pragma unroll
            for (int j = 0; j < 8; j++) {
                float2 bv = *reinterpret_cast<const float2*>(brow1 + j * H + h);
                a.x = fmaf(cc[8 + j], bv.x, a.x); a.y = fmaf(cc[8 + j], bv.y, a.y);
            }
            *reinterpret_cast<float2*>(op + h) = a;
        }
    }
}

extern "C" void kernel_launch(void* const* d_in, const int* in_sizes, int n_in,
                              void* d_out, int out_size, void* d_ws, size_t ws_size,
                              hipStream_t stream)
{
    const float* x  = (const float*)d_in[0];
    const float* bo = (const float*)d_in[1];
    const float* W1 = (const float*)d_in[2];
    const float* b1 = (const float*)d_in[3];
    const float* W2 = (const float*)d_in[4];
    const float* b2 = (const float*)d_in[5];
    const float* A  = (const float*)d_in[6];
    const float* Bm = (const float*)d_in[7];
    float* out = (float*)d_out;

    float* route_c   = (float*)d_ws;                                   // 32768*16 f32 = 2 MB
    int*   route_idx = (int*)((char*)d_ws + (size_t)NTOK * 16 * 4);    // 32768*2 i32 = 256 KB

    k_router<<<dim3(NTOK / 64), dim3(128), 0, stream>>>(
        x, W1, b1, W2, b2, A, route_c, route_idx);
    k_combine<<<dim3(256), dim3(512), 0, stream>>>(
        bo, Bm, route_c, route_idx, out);
}